// Round 3
// baseline (242.383 us; speedup 1.0000x reference)
//
#include <hip/hip_runtime.h>

#define K  100   // NUM_BREAKPOINTS
#define NB 1024  // LUT buckets (power of 2 -> exact fp bucket math)

typedef float fvec4 __attribute__((ext_vector_type(4)));

// ---------------------------------------------------------------------------
// Setup kernel (1 block, 1024 thr, ~1.5 µs): rank-sort breakpoints, scan betas,
// fold segments to y = a*x + b, build 1024-bucket direct table.
// Clean bucket (no interior breakpoint): (a, b) inline.
// Dirty bucket: (+inf marker, packed lo|hi<<16) -> rare linear-advance path.
// ws layout: [0,8192) float2 bab[NB] | [8192,8592) f32 sx[K]
//            [8704,9504) float2 ab[K]
// ---------------------------------------------------------------------------
__global__ __launch_bounds__(1024) void pwl_setup_kernel(
    const float* __restrict__ xp, const float* __restrict__ sl,
    const float* __restrict__ bias, float2* __restrict__ bab_g,
    float* __restrict__ sx_g, float2* __restrict__ ab_g) {
  __shared__ float s_pos[K];
  __shared__ float s_slope[K];
  __shared__ float s_sorted[K];
  __shared__ float s_a[K];
  __shared__ float s_b[K];
  __shared__ float s_scan[128];
  __shared__ unsigned short s_cnt[NB + 1];
  const int t = threadIdx.x;

  if (t < K) { s_pos[t] = xp[t]; s_slope[t] = sl[t]; }
  __syncthreads();

  // O(K^2) stable rank sort (ties broken by original index)
  if (t < K) {
    float v = s_pos[t];
    int r = 0;
    for (int j = 0; j < K; ++j) {
      float u = s_pos[j];
      r += ((u < v) || (u == v && j < t)) ? 1 : 0;
    }
    s_sorted[r] = v;
  }
  __syncthreads();

  // d[i] = (sorted[i+1]-sorted[i])*slope[i]; beta[i] = bias + sum_{j<i} d[j]
  // parallel Hillis-Steele inclusive scan over 128 slots (zero-padded)
  if (t < 128) {
    float d = 0.0f;
    if (t < K - 1) d = (s_sorted[t + 1] - s_sorted[t]) * s_slope[t];
    s_scan[t] = d;
  }
  __syncthreads();
  for (int off = 1; off < 128; off <<= 1) {
    float add = 0.0f;
    if (t < 128 && t >= off) add = s_scan[t - off];
    __syncthreads();
    if (t < 128) s_scan[t] += add;
    __syncthreads();
  }
  if (t < K) {
    float beta = bias[0] + (t ? s_scan[t - 1] : 0.0f);
    float a = s_slope[t];
    s_a[t] = a;
    s_b[t] = beta - s_sorted[t] * a;  // y = a*x + b on segment t
    sx_g[t] = s_sorted[t];
    ab_g[t] = make_float2(a, s_b[t]);
  }
  __syncthreads();

  // cnt at bucket edge e/NB: #sorted <= edge (edge value exact: pow2 scale)
  for (int e = t; e <= NB; e += blockDim.x) {
    float ev = (float)e * (1.0f / (float)NB);
    int c = 0;
    for (int j = 0; j < K; ++j) c += (s_sorted[j] <= ev) ? 1 : 0;
    s_cnt[e] = (unsigned short)c;
  }
  __syncthreads();

  for (int b = t; b < NB; b += blockDim.x) {
    int lo = s_cnt[b], hi = s_cnt[b + 1];
    float2 e;
    if (lo == hi) {                      // clean: segment fully determined
      int idx = min(max(lo, 1), K) - 1;  // clip(cnt,1,K)-1
      e = make_float2(s_a[idx], s_b[idx]);
    } else {                             // dirty: marker + packed range
      e.x = __builtin_huge_valf();
      e.y = __uint_as_float((unsigned)lo | ((unsigned)hi << 16));
    }
    bab_g[b] = e;
  }
}

// ---------------------------------------------------------------------------
// Main streaming kernel: memory-bound; one random ds_read_b64 per element on
// the common path; 2 independent float4 per loop iter for load overlap.
// ---------------------------------------------------------------------------
__device__ __forceinline__ float pwl_eval(float xv,
                                          const float2* __restrict__ s_bab,
                                          const float* __restrict__ s_x,
                                          const float2* __restrict__ s_ab) {
  int b = (int)(xv * (float)NB);
  b = min(max(b, 0), NB - 1);
  float2 ab = s_bab[b];
  if (__float_as_uint(ab.x) == 0x7f800000u) {  // dirty bucket (~9% of evals)
    unsigned p = __float_as_uint(ab.y);
    int lo = (int)(p & 0xffffu);
    int hi = (int)(p >> 16);
    while (lo < hi && s_x[lo] <= xv) ++lo;  // linear advance, ~1 trip typical
    int idx = min(max(lo, 1), K) - 1;
    ab = s_ab[idx];
  }
  return fminf(fmaxf(fmaf(xv, ab.x, ab.y), 0.0f), 1.0f);
}

__device__ __forceinline__ fvec4 eval4(fvec4 v,
                                       const float2* __restrict__ s_bab,
                                       const float* __restrict__ s_x,
                                       const float2* __restrict__ s_ab) {
  fvec4 r;
  r.x = pwl_eval(v.x, s_bab, s_x, s_ab);
  r.y = pwl_eval(v.y, s_bab, s_x, s_ab);
  r.z = pwl_eval(v.z, s_bab, s_x, s_ab);
  r.w = pwl_eval(v.w, s_bab, s_x, s_ab);
  return r;
}

__global__ __launch_bounds__(256) void pwl_main_kernel(
    const fvec4* __restrict__ x, const float2* __restrict__ bab_g,
    const float* __restrict__ sx_g, const float2* __restrict__ ab_g,
    fvec4* __restrict__ out, int n4, int n) {
  __shared__ float2 s_bab[NB];
  __shared__ float s_x[K];
  __shared__ float2 s_ab[K];
  for (int i = threadIdx.x; i < NB; i += blockDim.x) s_bab[i] = bab_g[i];
  if (threadIdx.x < K) {
    s_x[threadIdx.x] = sx_g[threadIdx.x];
    s_ab[threadIdx.x] = ab_g[threadIdx.x];
  }
  __syncthreads();

  const int stride = gridDim.x * blockDim.x;
  int i = blockIdx.x * blockDim.x + threadIdx.x;
  // 2 independent float4 per iteration: both loads issued before either eval
  for (; i + stride < n4; i += 2 * stride) {
    fvec4 v0 = __builtin_nontemporal_load(&x[i]);
    fvec4 v1 = __builtin_nontemporal_load(&x[i + stride]);
    fvec4 r0 = eval4(v0, s_bab, s_x, s_ab);
    fvec4 r1 = eval4(v1, s_bab, s_x, s_ab);
    __builtin_nontemporal_store(r0, &out[i]);
    __builtin_nontemporal_store(r1, &out[i + stride]);
  }
  if (i < n4) {
    fvec4 v = __builtin_nontemporal_load(&x[i]);
    __builtin_nontemporal_store(eval4(v, s_bab, s_x, s_ab), &out[i]);
  }

  // scalar tail (n % 4), block 0 (empty for this shape)
  if (blockIdx.x == 0) {
    const float* xs = (const float*)x;
    float* os = (float*)out;
    for (int j = (n4 << 2) + threadIdx.x; j < n; j += blockDim.x) {
      os[j] = pwl_eval(xs[j], s_bab, s_x, s_ab);
    }
  }
}

extern "C" void kernel_launch(void* const* d_in, const int* in_sizes, int n_in,
                              void* d_out, int out_size, void* d_ws, size_t ws_size,
                              hipStream_t stream) {
  const float* x    = (const float*)d_in[0];
  const float* xp   = (const float*)d_in[1];
  const float* sl   = (const float*)d_in[2];
  const float* bias = (const float*)d_in[3];
  float* out = (float*)d_out;

  float2* bab = (float2*)d_ws;                          // 8192 B
  float* sx   = (float*)((char*)d_ws + NB * 8);         // 400 B (+pad)
  float2* ab  = (float2*)((char*)d_ws + NB * 8 + 512);  // 800 B, 8B-aligned

  const int n  = in_sizes[0];
  const int n4 = n >> 2;

  pwl_setup_kernel<<<1, 1024, 0, stream>>>(xp, sl, bias, bab, sx, ab);

  const int threads = 256;
  const int blocks  = 2048;  // 8 blocks/CU * 1 wave-group each = 32 waves/CU
  pwl_main_kernel<<<blocks, threads, 0, stream>>>(
      (const fvec4*)x, bab, sx, ab, (fvec4*)out, n4, n);
}